// Round 11
// baseline (261.080 us; speedup 1.0000x reference)
//
#include <hip/hip_runtime.h>

typedef unsigned short u16;
typedef unsigned int   u32;

typedef __bf16 bf16x8 __attribute__((ext_vector_type(8)));
typedef float  f32x4  __attribute__((ext_vector_type(4)));

typedef const __attribute__((address_space(1))) u32 GAS;
typedef __attribute__((address_space(3))) u32 LAS;

__device__ __forceinline__ u16 f2bf(float f) {
  u32 u = __builtin_bit_cast(u32, f);
  return (u16)((u + 0x7FFFu + ((u >> 16) & 1u)) >> 16);
}

// Branchless fast tanh: t = 1 - 2/(e^{2|x|}+1), sign restored.
// Overflow-safe (e->inf => t->1).  |err| ~1e-6 << bf16 noise (0.031) and
// test threshold (0.119).  ~7 VALU ops vs ~30 for libm tanhf.  (R7-proven)
__device__ __forceinline__ float fast_tanh(float x) {
  const float a = fabsf(x);
  const float e = __expf(2.0f * a);
  const float t = 1.0f - 2.0f * __builtin_amdgcn_rcpf(e + 1.0f);
  return copysignf(t, x);
}

// ---------------------------------------------------------------------------
// X3[kblk][m][8] bf16, kblk = k/8, m in [0,4096), k in [0,6144):
//   seg0 [xr | hr], seg1 [xi | hi], seg2 [xr+xi | hr+hi]   (R0-proven)
// ---------------------------------------------------------------------------
__global__ __launch_bounds__(256) void build_x_k(
    const float* __restrict__ inp, const float* __restrict__ h,
    u16* __restrict__ X3) {
  __shared__ float t[64 * 65];  // t[k][m], pitch 65
  const int tid = threadIdx.x;
  const int tx = tid & 15, ty = tid >> 4;
  const int m0 = blockIdx.y * 64, k0 = blockIdx.x * 64;
  const int sel = k0 >> 10;          // uniform per block
  const int kc = k0 & 1023;
  const float* s1 = (sel == 0 || sel == 2 || sel == 4) ? inp : h;
  const int c1 = (sel == 2 || sel == 3) ? (1024 + kc) : kc;
  const bool pair = (sel >= 4);      // add column c1 + 1024 of same source
#pragma unroll
  for (int rr = 0; rr < 4; ++rr) {
    const int m = rr * 16 + ty;
    float4 v = *(const float4*)&s1[(size_t)(m0 + m) * 2048 + c1 + tx * 4];
    if (pair) {
      const float4 w = *(const float4*)&s1[(size_t)(m0 + m) * 2048 + c1 + 1024 + tx * 4];
      v.x += w.x; v.y += w.y; v.z += w.z; v.w += w.w;
    }
    t[(tx * 4 + 0) * 65 + m] = v.x;
    t[(tx * 4 + 1) * 65 + m] = v.y;
    t[(tx * 4 + 2) * 65 + m] = v.z;
    t[(tx * 4 + 3) * 65 + m] = v.w;
  }
  __syncthreads();
#pragma unroll
  for (int rep = 0; rep < 2; ++rep) {
    const int cell = rep * 256 + tid;       // 512 cells: kblk(8) x m(64)
    const int kblk = cell >> 6, m = cell & 63;
    union { u16 s[8]; uint4 v; } tmp;
#pragma unroll
    for (int i = 0; i < 8; ++i) tmp.s[i] = f2bf(t[(kblk * 8 + i) * 65 + m]);
    *(uint4*)&X3[((size_t)(k0 / 8 + kblk) * 4096 + m0 + m) * 8] = tmp.v;
  }
}

// ---------------------------------------------------------------------------
// W3[kblk][n][8] bf16, rows k in [0,6144): seg0 [Kr;Rr], seg1 [Ki;Ri],
// seg2 [Kr-Ki; Rr-Ri].  Cols n = (j>>4)*64 + g*16 + (j&15).   (R0-proven)
// ---------------------------------------------------------------------------
__global__ __launch_bounds__(256) void build_w_k(
    const float* __restrict__ Kr, const float* __restrict__ Ki,
    const float* __restrict__ Rr, const float* __restrict__ Ri,
    u16* __restrict__ W3) {
  __shared__ float t[4 * 1032];  // [g][k(64)][jlo(16)], per-g pitch 1032
  const int tid = threadIdx.x;
  const int tx = tid & 15, ty = tid >> 4;
  const int jhi = blockIdx.y;          // [0,64): 16-j group
  const int k0 = blockIdx.x * 64;      // [0,6144)
  const int sel = k0 >> 10;            // 0:Kr 1:Rr 2:Ki 3:Ri 4:Kr-Ki 5:Rr-Ri
  const int krow = k0 & 1023;
  const int jbase = jhi * 16;
  const float* sA = (sel == 0) ? Kr : (sel == 1) ? Rr : (sel == 2) ? Ki
                  : (sel == 3) ? Ri : (sel == 4) ? Kr : Rr;
  const float* sB = (sel == 4) ? Ki : (sel == 5) ? Ri : nullptr;
#pragma unroll
  for (int g = 0; g < 4; ++g) {
    const int cs = g * 1024 + jbase + tx;
#pragma unroll
    for (int rr = 0; rr < 4; ++rr) {
      const int k = rr * 16 + ty;
      float v = sA[(size_t)(krow + k) * 4096 + cs];
      if (sel >= 4) v -= sB[(size_t)(krow + k) * 4096 + cs];
      t[g * 1032 + k * 16 + tx] = v;
    }
  }
  __syncthreads();
#pragma unroll
  for (int rep = 0; rep < 2; ++rep) {
    const int cell = rep * 256 + tid;       // 512 cells: kblk(8) x n(64)
    const int kblk = cell >> 6, n = cell & 63;
    const int g = n >> 4, jlo = n & 15;
    union { u16 s[8]; uint4 v; } tmp;
#pragma unroll
    for (int i = 0; i < 8; ++i)
      tmp.s[i] = f2bf(t[g * 1032 + (kblk * 8 + i) * 16 + jlo]);
    *(uint4*)&W3[((size_t)(k0 / 8 + kblk) * 4096 + (size_t)jhi * 64 + n) * 8] = tmp.v;
  }
}

// ---------------------------------------------------------------------------
// Gauss 3-product GEMM (M=4096, Kg=6144, Npacked=4096) + fused CLSTM epilogue.
// R11 = R7 byte-identical (pre-committed revert after R8/R9/R10 failures on
// the 2-blocks/CU structure).  Sync skeleton, ring-10, staging, fast_tanh
// epilogue all R6/R7-proven.  Full design rationale/ledger: see R6.
// ---------------------------------------------------------------------------
#define NKT 96

#define MFMA16G(AV, BQ, ACC)                                                \
  __builtin_amdgcn_s_setprio(1);                                            \
  _Pragma("unroll")                                                         \
  for (int mf = 0; mf < 4; ++mf)                                            \
    _Pragma("unroll")                                                       \
    for (int n = 0; n < 4; ++n)                                             \
      ACC[mf][n] = __builtin_amdgcn_mfma_f32_16x16x32_bf16(                 \
          AV[mf], BQ[n], ACC[mf][n], 0, 0, 0);                              \
  __builtin_amdgcn_s_setprio(0);

#define KTBODY(ACC)                                                         \
  {                                                                         \
    const u16* LA = L + (size_t)rb * 8192;                                  \
    int sBw = rb + 1 + (wc >> 1); if (sBw >= 10) sBw -= 10;                 \
    const u16* LBw = L + (size_t)sBw * 8192;                                \
    /* ---- phase 0 ---- */                                                 \
    __builtin_amdgcn_s_barrier();                                           \
    if (kt + 2 < NKT) {                                                     \
      stageA3(kt + 2, ss);                                                  \
      int s1 = ss + 1; if (s1 >= 10) s1 -= 10;                              \
      stageB3(kt + 2, 0, s1);                                               \
    }                                                                       \
    _Pragma("unroll")                                                       \
    for (int mf = 0; mf < 4; ++mf)                                          \
      avB[mf] = *(const bf16x8*)&LA[aoff + 4096 + mf * 128];                \
    _Pragma("unroll")                                                       \
    for (int n = 0; n < 4; ++n)                                             \
      bqB[n] = *(const bf16x8*)&LBw[boff + 4096 + n * 128];                 \
    asm volatile("s_waitcnt lgkmcnt(8)" ::: "memory");                      \
    MFMA16G(avA, bqA, ACC)                                                  \
    /* ---- phase 1 ---- */                                                 \
    if (kt + 2 < NKT) {                                                     \
      int s2 = ss + 2; if (s2 >= 10) s2 -= 10;                              \
      stageB3(kt + 2, 1, s2);                                               \
    }                                                                       \
    if (kt < NKT - 2)       asm volatile("s_waitcnt vmcnt(6)" ::: "memory");\
    else if (kt == NKT - 2) asm volatile("s_waitcnt vmcnt(0)" ::: "memory");\
    __builtin_amdgcn_s_barrier();                                           \
    if (kt + 1 < NKT) {                                                     \
      int rb2 = rb + 3; if (rb2 >= 10) rb2 -= 10;                           \
      const u16* LA2 = L + (size_t)rb2 * 8192;                              \
      int sBw2 = rb2 + 1 + (wc >> 1); if (sBw2 >= 10) sBw2 -= 10;           \
      const u16* LBw2 = L + (size_t)sBw2 * 8192;                            \
      _Pragma("unroll")                                                     \
      for (int mf = 0; mf < 4; ++mf)                                        \
        avA[mf] = *(const bf16x8*)&LA2[aoff + mf * 128];                    \
      _Pragma("unroll")                                                     \
      for (int n = 0; n < 4; ++n)                                           \
        bqA[n] = *(const bf16x8*)&LBw2[boff + n * 128];                     \
      asm volatile("s_waitcnt lgkmcnt(8)" ::: "memory");                    \
    } else {                                                                \
      asm volatile("s_waitcnt lgkmcnt(0)" ::: "memory");                    \
    }                                                                       \
    MFMA16G(avB, bqB, ACC)                                                  \
    rb += 3; if (rb >= 10) rb -= 10;                                        \
    ss += 3; if (ss >= 10) ss -= 10;                                        \
  }

__global__ __launch_bounds__(512, 2) void clstm_gemm_k(
    const u16* __restrict__ X3, const u16* __restrict__ W3,
    const float* __restrict__ cprev, const float* __restrict__ rb_,
    const float* __restrict__ ib_, float* __restrict__ out) {
  __shared__ __align__(16) u16 lds[10][8192];  // 10 regions x 16 KiB = 160 KiB
  const int tid = threadIdx.x;
  const int lane = tid & 63, wave = tid >> 6;
  const int wr = wave >> 2, wc = wave & 3;  // 2M x 4N wave grid
  const int orig = blockIdx.x;
  const int wg = (orig & 7) * 64 + (orig >> 3);  // T1 (512 % 8 == 0)
  const int mb = wg & 31, nb = wg >> 5;  // A streams (32/XCD), B shared (2/XCD)
  const int m0 = mb * 128, n0 = nb * 256;
  const u16* L = &lds[0][0];

  f32x4 a1[4][4] = {}, a2[4][4] = {};  // 2 Gauss banks, 64 f32 each

  // A region [kblk(8)][m(128)][8]; per wave: kblk = wave, 2 x 1 KiB chunks
  auto stageA3 = [&](int kt2, int slot) {
    const u16* s = X3 + ((size_t)(kt2 * 8 + wave) * 4096 + m0 + lane) * 8;
    __builtin_amdgcn_global_load_lds((GAS*)s, (LAS*)&lds[slot][(wave * 128) * 8], 16, 0, 0);
    __builtin_amdgcn_global_load_lds((GAS*)(s + 512), (LAS*)&lds[slot][(wave * 128 + 64) * 8], 16, 0, 0);
  };
  // B half-region [kblk(8)][n(128)][8], hf = 0 (cols n0..) / 1 (n0+128..)
  auto stageB3 = [&](int kt2, int hf, int slot) {
    const u16* s = W3 + ((size_t)(kt2 * 8 + wave) * 4096 + n0 + hf * 128 + lane) * 8;
    __builtin_amdgcn_global_load_lds((GAS*)s, (LAS*)&lds[slot][(wave * 128) * 8], 16, 0, 0);
    __builtin_amdgcn_global_load_lds((GAS*)(s + 512), (LAS*)&lds[slot][(wave * 128 + 64) * 8], 16, 0, 0);
  };

  const int hi = lane >> 4, lo = lane & 15;
  const int aoff = (hi * 128 + wr * 64 + lo) * 8;           // + ks*4096 + mf*128
  const int boff = (hi * 128 + (wc & 1) * 64 + lo) * 8;     // + ks*4096 + n*128

  // ---- prologue: kt0 (slots 0..2) + kt1 (slots 3..5) ----
  stageA3(0, 0); stageB3(0, 0, 1); stageB3(0, 1, 2);
  stageA3(1, 3); stageB3(1, 0, 4); stageB3(1, 1, 5);
  asm volatile("s_waitcnt vmcnt(6)" ::: "memory");  // kt0's 6 loads landed
  __builtin_amdgcn_s_barrier();

  bf16x8 avA[4], avB[4], bqA[4], bqB[4];
  {  // preload kt0 ks0 frag bank
    const u16* LA = L;
    const u16* LBw = L + (size_t)(1 + (wc >> 1)) * 8192;
#pragma unroll
    for (int mf = 0; mf < 4; ++mf) avA[mf] = *(const bf16x8*)&LA[aoff + mf * 128];
#pragma unroll
    for (int n = 0; n < 4; ++n)    bqA[n]  = *(const bf16x8*)&LBw[boff + n * 128];
  }

  int rb = 0, ss = 6, kt;
  for (kt = 0; kt < 32; ++kt) KTBODY(a1)   // segment 1 -> P1
  for (kt = 32; kt < 64; ++kt) KTBODY(a2)  // segment 2 -> P2
  // ---- merge: a1 = P1+P2 (zr-pre), a2 = P2-P1 ----
#pragma unroll
  for (int mf = 0; mf < 4; ++mf)
#pragma unroll
    for (int n = 0; n < 4; ++n) {
      const f32x4 t0 = a1[mf][n];
      a1[mf][n] = t0 + a2[mf][n];
      a2[mf][n] = a2[mf][n] - t0;
    }
  for (kt = 64; kt < NKT; ++kt) KTBODY(a2) // segment 3 -> a2 += P3 = zi-pre

  // ---- fused CLSTM epilogue (R0-proven layout; fast_tanh) ----
  const int j = (nb * 4 + wc) * 16 + lo;   // output column in [0,1024)
  float rbias[4], ibias[4];
#pragma unroll
  for (int g = 0; g < 4; ++g) {
    rbias[g] = rb_[g * 1024 + j];
    ibias[g] = ib_[g * 1024 + j];
  }
#pragma unroll
  for (int mf = 0; mf < 4; ++mf) {
    const int rowb = m0 + wr * 64 + mf * 16 + hi * 4;
#pragma unroll
    for (int r = 0; r < 4; ++r) {
      const size_t row = (size_t)(rowb + r);
      // real half: output cols [0,1024)
      {
        const float z0 = a1[mf][0][r] + rbias[0];
        const float z1 = a1[mf][1][r] + rbias[1];
        const float z2 = a1[mf][2][r] + rbias[2];
        const float z3 = a1[mf][3][r] + rbias[3];
        const float ig = fminf(fmaxf(0.2f * z0 + 0.5f, 0.0f), 1.0f);
        const float fg = fminf(fmaxf(0.2f * z1 + 0.5f, 0.0f), 1.0f);
        const float og = fminf(fmaxf(0.2f * z3 + 0.5f, 0.0f), 1.0f);
        const float cp = cprev[row * 2048 + j];
        const float cn = fg * cp + ig * fast_tanh(z2);
        const float hn = og * fast_tanh(cn);
        out[row * 2048 + j] = hn;
        out[(size_t)8388608 + row * 2048 + j] = cn;
      }
      // imaginary half: output cols [1024,2048)
      {
        const float z0 = a2[mf][0][r] + ibias[0];
        const float z1 = a2[mf][1][r] + ibias[1];
        const float z2 = a2[mf][2][r] + ibias[2];
        const float z3 = a2[mf][3][r] + ibias[3];
        const float ig = fminf(fmaxf(0.2f * z0 + 0.5f, 0.0f), 1.0f);
        const float fg = fminf(fmaxf(0.2f * z1 + 0.5f, 0.0f), 1.0f);
        const float og = fminf(fmaxf(0.2f * z3 + 0.5f, 0.0f), 1.0f);
        const float cp = cprev[row * 2048 + 1024 + j];
        const float cn = fg * cp + ig * fast_tanh(z2);
        const float hn = og * fast_tanh(cn);
        out[row * 2048 + 1024 + j] = hn;
        out[(size_t)8388608 + row * 2048 + 1024 + j] = cn;
      }
    }
  }
}

extern "C" void kernel_launch(void* const* d_in, const int* in_sizes, int n_in,
                              void* d_out, int out_size, void* d_ws, size_t ws_size,
                              hipStream_t stream) {
  const float* inputs = (const float*)d_in[0];
  const float* h_tm1  = (const float*)d_in[1];
  const float* c_tm1  = (const float*)d_in[2];
  const float* Kr     = (const float*)d_in[3];
  const float* Ki     = (const float*)d_in[4];
  const float* Rr     = (const float*)d_in[5];
  const float* Ri     = (const float*)d_in[6];
  const float* rb     = (const float*)d_in[7];
  const float* ib     = (const float*)d_in[8];
  float* out = (float*)d_out;

  u16* X3 = (u16*)d_ws;                       // 768*4096*8 u16 = 48 MiB
  u16* W3 = X3 + (size_t)768 * 4096 * 8;      // 768*4096*8 u16 = 48 MiB

  build_x_k<<<dim3(96, 64), 256, 0, stream>>>(inputs, h_tm1, X3);
  build_w_k<<<dim3(96, 64), 256, 0, stream>>>(Kr, Ki, Rr, Ri, W3);
  clstm_gemm_k<<<dim3(512, 1), 512, 0, stream>>>(X3, W3, c_tm1, rb, ib, out);
}

// Round 13
// 260.150 us; speedup vs baseline: 1.0036x; 1.0036x over previous
//
#include <hip/hip_runtime.h>

typedef unsigned short u16;
typedef unsigned int   u32;

typedef __bf16 bf16x8 __attribute__((ext_vector_type(8)));
typedef float  f32x4  __attribute__((ext_vector_type(4)));

typedef const __attribute__((address_space(1))) u32 GAS;
typedef __attribute__((address_space(3))) u32 LAS;

__device__ __forceinline__ u16 f2bf(float f) {
  u32 u = __builtin_bit_cast(u32, f);
  return (u16)((u + 0x7FFFu + ((u >> 16) & 1u)) >> 16);
}

// Branchless fast tanh: t = 1 - 2/(e^{2|x|}+1), sign restored.
// Overflow-safe (e->inf => t->1).  |err| ~1e-6 << bf16 noise (0.031) and
// test threshold (0.119).  ~7 VALU ops vs ~30 for libm tanhf.  (R7-proven)
__device__ __forceinline__ float fast_tanh(float x) {
  const float a = fabsf(x);
  const float e = __expf(2.0f * a);
  const float t = 1.0f - 2.0f * __builtin_amdgcn_rcpf(e + 1.0f);
  return copysignf(t, x);
}

// ---------------------------------------------------------------------------
// X3[kblk][m][8] bf16, kblk = k/8, m in [0,4096), k in [0,6144):
//   seg0 [xr | hr], seg1 [xi | hi], seg2 [xr+xi | hr+hi]   (R0-proven)
// ---------------------------------------------------------------------------
__global__ __launch_bounds__(256) void build_x_k(
    const float* __restrict__ inp, const float* __restrict__ h,
    u16* __restrict__ X3) {
  __shared__ float t[64 * 65];  // t[k][m], pitch 65
  const int tid = threadIdx.x;
  const int tx = tid & 15, ty = tid >> 4;
  const int m0 = blockIdx.y * 64, k0 = blockIdx.x * 64;
  const int sel = k0 >> 10;          // uniform per block
  const int kc = k0 & 1023;
  const float* s1 = (sel == 0 || sel == 2 || sel == 4) ? inp : h;
  const int c1 = (sel == 2 || sel == 3) ? (1024 + kc) : kc;
  const bool pair = (sel >= 4);      // add column c1 + 1024 of same source
#pragma unroll
  for (int rr = 0; rr < 4; ++rr) {
    const int m = rr * 16 + ty;
    float4 v = *(const float4*)&s1[(size_t)(m0 + m) * 2048 + c1 + tx * 4];
    if (pair) {
      const float4 w = *(const float4*)&s1[(size_t)(m0 + m) * 2048 + c1 + 1024 + tx * 4];
      v.x += w.x; v.y += w.y; v.z += w.z; v.w += w.w;
    }
    t[(tx * 4 + 0) * 65 + m] = v.x;
    t[(tx * 4 + 1) * 65 + m] = v.y;
    t[(tx * 4 + 2) * 65 + m] = v.z;
    t[(tx * 4 + 3) * 65 + m] = v.w;
  }
  __syncthreads();
#pragma unroll
  for (int rep = 0; rep < 2; ++rep) {
    const int cell = rep * 256 + tid;       // 512 cells: kblk(8) x m(64)
    const int kblk = cell >> 6, m = cell & 63;
    union { u16 s[8]; uint4 v; } tmp;
#pragma unroll
    for (int i = 0; i < 8; ++i) tmp.s[i] = f2bf(t[(kblk * 8 + i) * 65 + m]);
    *(uint4*)&X3[((size_t)(k0 / 8 + kblk) * 4096 + m0 + m) * 8] = tmp.v;
  }
}

// ---------------------------------------------------------------------------
// W3[kblk][n][8] bf16, rows k in [0,6144): seg0 [Kr;Rr], seg1 [Ki;Ri],
// seg2 [Kr-Ki; Rr-Ri].  Cols n = (j>>4)*64 + g*16 + (j&15).   (R0-proven)
// ---------------------------------------------------------------------------
__global__ __launch_bounds__(256) void build_w_k(
    const float* __restrict__ Kr, const float* __restrict__ Ki,
    const float* __restrict__ Rr, const float* __restrict__ Ri,
    u16* __restrict__ W3) {
  __shared__ float t[4 * 1032];  // [g][k(64)][jlo(16)], per-g pitch 1032
  const int tid = threadIdx.x;
  const int tx = tid & 15, ty = tid >> 4;
  const int jhi = blockIdx.y;          // [0,64): 16-j group
  const int k0 = blockIdx.x * 64;      // [0,6144)
  const int sel = k0 >> 10;            // 0:Kr 1:Rr 2:Ki 3:Ri 4:Kr-Ki 5:Rr-Ri
  const int krow = k0 & 1023;
  const int jbase = jhi * 16;
  const float* sA = (sel == 0) ? Kr : (sel == 1) ? Rr : (sel == 2) ? Ki
                  : (sel == 3) ? Ri : (sel == 4) ? Kr : Rr;
  const float* sB = (sel == 4) ? Ki : (sel == 5) ? Ri : nullptr;
#pragma unroll
  for (int g = 0; g < 4; ++g) {
    const int cs = g * 1024 + jbase + tx;
#pragma unroll
    for (int rr = 0; rr < 4; ++rr) {
      const int k = rr * 16 + ty;
      float v = sA[(size_t)(krow + k) * 4096 + cs];
      if (sel >= 4) v -= sB[(size_t)(krow + k) * 4096 + cs];
      t[g * 1032 + k * 16 + tx] = v;
    }
  }
  __syncthreads();
#pragma unroll
  for (int rep = 0; rep < 2; ++rep) {
    const int cell = rep * 256 + tid;       // 512 cells: kblk(8) x n(64)
    const int kblk = cell >> 6, n = cell & 63;
    const int g = n >> 4, jlo = n & 15;
    union { u16 s[8]; uint4 v; } tmp;
#pragma unroll
    for (int i = 0; i < 8; ++i)
      tmp.s[i] = f2bf(t[g * 1032 + (kblk * 8 + i) * 16 + jlo]);
    *(uint4*)&W3[((size_t)(k0 / 8 + kblk) * 4096 + (size_t)jhi * 64 + n) * 8] = tmp.v;
  }
}

// ---------------------------------------------------------------------------
// Gauss 3-product GEMM (M=4096, Kg=6144, Npacked=4096) + fused CLSTM epilogue.
// R13 = R7/R11 byte-identical (final; pre-committed revert after the 2-blk/CU
// lineage failed 4x under 3 sync regimes).  Sync skeleton, ring-10, staging,
// fast_tanh epilogue all R6/R7-proven.  Full design rationale/ledger: see R6.
// ---------------------------------------------------------------------------
#define NKT 96

#define MFMA16G(AV, BQ, ACC)                                                \
  __builtin_amdgcn_s_setprio(1);                                            \
  _Pragma("unroll")                                                         \
  for (int mf = 0; mf < 4; ++mf)                                            \
    _Pragma("unroll")                                                       \
    for (int n = 0; n < 4; ++n)                                             \
      ACC[mf][n] = __builtin_amdgcn_mfma_f32_16x16x32_bf16(                 \
          AV[mf], BQ[n], ACC[mf][n], 0, 0, 0);                              \
  __builtin_amdgcn_s_setprio(0);

#define KTBODY(ACC)                                                         \
  {                                                                         \
    const u16* LA = L + (size_t)rb * 8192;                                  \
    int sBw = rb + 1 + (wc >> 1); if (sBw >= 10) sBw -= 10;                 \
    const u16* LBw = L + (size_t)sBw * 8192;                                \
    /* ---- phase 0 ---- */                                                 \
    __builtin_amdgcn_s_barrier();                                           \
    if (kt + 2 < NKT) {                                                     \
      stageA3(kt + 2, ss);                                                  \
      int s1 = ss + 1; if (s1 >= 10) s1 -= 10;                              \
      stageB3(kt + 2, 0, s1);                                               \
    }                                                                       \
    _Pragma("unroll")                                                       \
    for (int mf = 0; mf < 4; ++mf)                                          \
      avB[mf] = *(const bf16x8*)&LA[aoff + 4096 + mf * 128];                \
    _Pragma("unroll")                                                       \
    for (int n = 0; n < 4; ++n)                                             \
      bqB[n] = *(const bf16x8*)&LBw[boff + 4096 + n * 128];                 \
    asm volatile("s_waitcnt lgkmcnt(8)" ::: "memory");                      \
    MFMA16G(avA, bqA, ACC)                                                  \
    /* ---- phase 1 ---- */                                                 \
    if (kt + 2 < NKT) {                                                     \
      int s2 = ss + 2; if (s2 >= 10) s2 -= 10;                              \
      stageB3(kt + 2, 1, s2);                                               \
    }                                                                       \
    if (kt < NKT - 2)       asm volatile("s_waitcnt vmcnt(6)" ::: "memory");\
    else if (kt == NKT - 2) asm volatile("s_waitcnt vmcnt(0)" ::: "memory");\
    __builtin_amdgcn_s_barrier();                                           \
    if (kt + 1 < NKT) {                                                     \
      int rb2 = rb + 3; if (rb2 >= 10) rb2 -= 10;                           \
      const u16* LA2 = L + (size_t)rb2 * 8192;                              \
      int sBw2 = rb2 + 1 + (wc >> 1); if (sBw2 >= 10) sBw2 -= 10;           \
      const u16* LBw2 = L + (size_t)sBw2 * 8192;                            \
      _Pragma("unroll")                                                     \
      for (int mf = 0; mf < 4; ++mf)                                        \
        avA[mf] = *(const bf16x8*)&LA2[aoff + mf * 128];                    \
      _Pragma("unroll")                                                     \
      for (int n = 0; n < 4; ++n)                                           \
        bqA[n] = *(const bf16x8*)&LBw2[boff + n * 128];                     \
      asm volatile("s_waitcnt lgkmcnt(8)" ::: "memory");                    \
    } else {                                                                \
      asm volatile("s_waitcnt lgkmcnt(0)" ::: "memory");                    \
    }                                                                       \
    MFMA16G(avB, bqB, ACC)                                                  \
    rb += 3; if (rb >= 10) rb -= 10;                                        \
    ss += 3; if (ss >= 10) ss -= 10;                                        \
  }

__global__ __launch_bounds__(512, 2) void clstm_gemm_k(
    const u16* __restrict__ X3, const u16* __restrict__ W3,
    const float* __restrict__ cprev, const float* __restrict__ rb_,
    const float* __restrict__ ib_, float* __restrict__ out) {
  __shared__ __align__(16) u16 lds[10][8192];  // 10 regions x 16 KiB = 160 KiB
  const int tid = threadIdx.x;
  const int lane = tid & 63, wave = tid >> 6;
  const int wr = wave >> 2, wc = wave & 3;  // 2M x 4N wave grid
  const int orig = blockIdx.x;
  const int wg = (orig & 7) * 64 + (orig >> 3);  // T1 (512 % 8 == 0)
  const int mb = wg & 31, nb = wg >> 5;  // A streams (32/XCD), B shared (2/XCD)
  const int m0 = mb * 128, n0 = nb * 256;
  const u16* L = &lds[0][0];

  f32x4 a1[4][4] = {}, a2[4][4] = {};  // 2 Gauss banks, 64 f32 each

  // A region [kblk(8)][m(128)][8]; per wave: kblk = wave, 2 x 1 KiB chunks
  auto stageA3 = [&](int kt2, int slot) {
    const u16* s = X3 + ((size_t)(kt2 * 8 + wave) * 4096 + m0 + lane) * 8;
    __builtin_amdgcn_global_load_lds((GAS*)s, (LAS*)&lds[slot][(wave * 128) * 8], 16, 0, 0);
    __builtin_amdgcn_global_load_lds((GAS*)(s + 512), (LAS*)&lds[slot][(wave * 128 + 64) * 8], 16, 0, 0);
  };
  // B half-region [kblk(8)][n(128)][8], hf = 0 (cols n0..) / 1 (n0+128..)
  auto stageB3 = [&](int kt2, int hf, int slot) {
    const u16* s = W3 + ((size_t)(kt2 * 8 + wave) * 4096 + n0 + hf * 128 + lane) * 8;
    __builtin_amdgcn_global_load_lds((GAS*)s, (LAS*)&lds[slot][(wave * 128) * 8], 16, 0, 0);
    __builtin_amdgcn_global_load_lds((GAS*)(s + 512), (LAS*)&lds[slot][(wave * 128 + 64) * 8], 16, 0, 0);
  };

  const int hi = lane >> 4, lo = lane & 15;
  const int aoff = (hi * 128 + wr * 64 + lo) * 8;           // + ks*4096 + mf*128
  const int boff = (hi * 128 + (wc & 1) * 64 + lo) * 8;     // + ks*4096 + n*128

  // ---- prologue: kt0 (slots 0..2) + kt1 (slots 3..5) ----
  stageA3(0, 0); stageB3(0, 0, 1); stageB3(0, 1, 2);
  stageA3(1, 3); stageB3(1, 0, 4); stageB3(1, 1, 5);
  asm volatile("s_waitcnt vmcnt(6)" ::: "memory");  // kt0's 6 loads landed
  __builtin_amdgcn_s_barrier();

  bf16x8 avA[4], avB[4], bqA[4], bqB[4];
  {  // preload kt0 ks0 frag bank
    const u16* LA = L;
    const u16* LBw = L + (size_t)(1 + (wc >> 1)) * 8192;
#pragma unroll
    for (int mf = 0; mf < 4; ++mf) avA[mf] = *(const bf16x8*)&LA[aoff + mf * 128];
#pragma unroll
    for (int n = 0; n < 4; ++n)    bqA[n]  = *(const bf16x8*)&LBw[boff + n * 128];
  }

  int rb = 0, ss = 6, kt;
  for (kt = 0; kt < 32; ++kt) KTBODY(a1)   // segment 1 -> P1
  for (kt = 32; kt < 64; ++kt) KTBODY(a2)  // segment 2 -> P2
  // ---- merge: a1 = P1+P2 (zr-pre), a2 = P2-P1 ----
#pragma unroll
  for (int mf = 0; mf < 4; ++mf)
#pragma unroll
    for (int n = 0; n < 4; ++n) {
      const f32x4 t0 = a1[mf][n];
      a1[mf][n] = t0 + a2[mf][n];
      a2[mf][n] = a2[mf][n] - t0;
    }
  for (kt = 64; kt < NKT; ++kt) KTBODY(a2) // segment 3 -> a2 += P3 = zi-pre

  // ---- fused CLSTM epilogue (R0-proven layout; fast_tanh) ----
  const int j = (nb * 4 + wc) * 16 + lo;   // output column in [0,1024)
  float rbias[4], ibias[4];
#pragma unroll
  for (int g = 0; g < 4; ++g) {
    rbias[g] = rb_[g * 1024 + j];
    ibias[g] = ib_[g * 1024 + j];
  }
#pragma unroll
  for (int mf = 0; mf < 4; ++mf) {
    const int rowb = m0 + wr * 64 + mf * 16 + hi * 4;
#pragma unroll
    for (int r = 0; r < 4; ++r) {
      const size_t row = (size_t)(rowb + r);
      // real half: output cols [0,1024)
      {
        const float z0 = a1[mf][0][r] + rbias[0];
        const float z1 = a1[mf][1][r] + rbias[1];
        const float z2 = a1[mf][2][r] + rbias[2];
        const float z3 = a1[mf][3][r] + rbias[3];
        const float ig = fminf(fmaxf(0.2f * z0 + 0.5f, 0.0f), 1.0f);
        const float fg = fminf(fmaxf(0.2f * z1 + 0.5f, 0.0f), 1.0f);
        const float og = fminf(fmaxf(0.2f * z3 + 0.5f, 0.0f), 1.0f);
        const float cp = cprev[row * 2048 + j];
        const float cn = fg * cp + ig * fast_tanh(z2);
        const float hn = og * fast_tanh(cn);
        out[row * 2048 + j] = hn;
        out[(size_t)8388608 + row * 2048 + j] = cn;
      }
      // imaginary half: output cols [1024,2048)
      {
        const float z0 = a2[mf][0][r] + ibias[0];
        const float z1 = a2[mf][1][r] + ibias[1];
        const float z2 = a2[mf][2][r] + ibias[2];
        const float z3 = a2[mf][3][r] + ibias[3];
        const float ig = fminf(fmaxf(0.2f * z0 + 0.5f, 0.0f), 1.0f);
        const float fg = fminf(fmaxf(0.2f * z1 + 0.5f, 0.0f), 1.0f);
        const float og = fminf(fmaxf(0.2f * z3 + 0.5f, 0.0f), 1.0f);
        const float cp = cprev[row * 2048 + 1024 + j];
        const float cn = fg * cp + ig * fast_tanh(z2);
        const float hn = og * fast_tanh(cn);
        out[row * 2048 + 1024 + j] = hn;
        out[(size_t)8388608 + row * 2048 + 1024 + j] = cn;
      }
    }
  }
}

extern "C" void kernel_launch(void* const* d_in, const int* in_sizes, int n_in,
                              void* d_out, int out_size, void* d_ws, size_t ws_size,
                              hipStream_t stream) {
  const float* inputs = (const float*)d_in[0];
  const float* h_tm1  = (const float*)d_in[1];
  const float* c_tm1  = (const float*)d_in[2];
  const float* Kr     = (const float*)d_in[3];
  const float* Ki     = (const float*)d_in[4];
  const float* Rr     = (const float*)d_in[5];
  const float* Ri     = (const float*)d_in[6];
  const float* rb     = (const float*)d_in[7];
  const float* ib     = (const float*)d_in[8];
  float* out = (float*)d_out;

  u16* X3 = (u16*)d_ws;                       // 768*4096*8 u16 = 48 MiB
  u16* W3 = X3 + (size_t)768 * 4096 * 8;      // 768*4096*8 u16 = 48 MiB

  build_x_k<<<dim3(96, 64), 256, 0, stream>>>(inputs, h_tm1, X3);
  build_w_k<<<dim3(96, 64), 256, 0, stream>>>(Kr, Ki, Rr, Ri, W3);
  clstm_gemm_k<<<dim3(512, 1), 512, 0, stream>>>(X3, W3, c_tm1, rb, ib, out);
}